// Round 7
// baseline (411.378 us; speedup 1.0000x reference)
//
#include <hip/hip_runtime.h>
#include <hip/hip_bf16.h>
#include <cstdint>

// ---------------------------------------------------------------------------
// Sampled DCT2: (1) luminance + per-8x8-block 2D DCT -> [64,1,512,512]
//               (2) exact JAX threefry permutation sampling -> [64,64,250]
//
// R11: fused structure retained (R6: 184us fused beat serial R4 total).
// Two surgical fixes to the incumbent:
//  * dct path register fit: R6 reported VGPR=32 vs a ~55-60 live set
//    (acc[4][8]+y[8]+loads) => allocator spilled to scratch. Now 4 row-pair
//    passes (acc[2][8]=16 regs, peak live ~40) -- guaranteed no-spill under
//    the 64-VGPR cap. Input re-read x4 is L3-absorbed (R6: FETCH 192MB for
//    402MB logical reads).
//  * sample hist: packed-u16 -> u32[4096]. Removes shift/mask VALU from
//    atomic+ord, scatter-start and select probes on a VALU-bound path.
//    Counts <= 4096; pure representation change, ranks bit-identical.
//    LDS 25.6 -> 33.3 KB, still 4 WG/CU.
//
// Sample algorithm (verified bit-exact): inverse-select over two counting
// builds; select(s) = binary search of inclusive ends + k-th smallest of
// the (avg len 1) bucket run; final[s] = select0(select1(s)). Writes 250
// absolute img offsets to ws; trailing gather kernel resolves them (breaks
// the dct->sample data hazard without a grid sync).
// R3 lesson: generic rotl -> compiler picks v_alignbit / SALU; don't force.
// R5 lesson: no LDS/barriers in the dct path (DS-pipe contention with
// sample's atomics).
// ---------------------------------------------------------------------------

#define BATCH 64
#define HW 512
#define NBLK 4096
#define NSAMPLE 250
#define IMG_ELEMS (HW * HW)

#define A0 0.35355339059327373f
#define A1 0.49039264020161522f
#define A2 0.46193976625564337f
#define A3 0.41573480615127262f
#define A4 0.35355339059327379f
#define A5 0.27778511650980111f
#define A6 0.19134171618254492f
#define A7 0.09754516100806412f

__constant__ float Qc[8][8] = {
    { A0,  A0,  A0,  A0,  A0,  A0,  A0,  A0},
    { A1,  A3,  A5,  A7, -A7, -A5, -A3, -A1},
    { A2,  A6, -A6, -A2, -A2, -A6,  A6,  A2},
    { A3, -A7, -A1, -A5,  A5,  A1,  A7, -A3},
    { A4, -A4, -A4,  A4,  A4, -A4, -A4,  A4},
    { A5, -A1,  A7,  A3, -A3, -A7,  A1, -A5},
    { A6, -A2,  A2, -A6, -A6,  A2, -A2,  A6},
    { A7, -A5,  A3, -A1,  A1, -A3,  A5, -A7},
};

__constant__ int ZIGZAG[64] = {
    0, 1, 8, 16, 9, 2, 3, 10, 17, 24, 32, 25, 18, 11, 4, 5,
    12, 19, 26, 33, 40, 48, 41, 34, 27, 20, 13, 6, 7, 14, 21, 28,
    35, 42, 49, 56, 57, 50, 43, 36, 29, 22, 15, 23, 30, 37, 44, 51,
    58, 59, 52, 45, 38, 31, 39, 46, 53, 60, 61, 54, 47, 55, 62, 63
};

// ---------------- Threefry-2x32 (exact JAX rounds) -------------------------
__device__ __forceinline__ uint32_t rotl32(uint32_t v, int d) {
    return (v << d) | (v >> (32 - d));
}

__device__ __forceinline__ void tf2x32(uint32_t k0, uint32_t k1,
                                       uint32_t x0, uint32_t x1,
                                       uint32_t& o0, uint32_t& o1) {
    uint32_t ks0 = k0, ks1 = k1, ks2 = k0 ^ k1 ^ 0x1BD11BDAu;
    x0 += ks0; x1 += ks1;
#define TF_R(r) { x0 += x1; x1 = rotl32(x1, r); x1 ^= x0; }
    TF_R(13) TF_R(15) TF_R(26) TF_R(6)
    x0 += ks1; x1 += ks2 + 1u;
    TF_R(17) TF_R(29) TF_R(16) TF_R(24)
    x0 += ks2; x1 += ks0 + 2u;
    TF_R(13) TF_R(15) TF_R(26) TF_R(6)
    x0 += ks0; x1 += ks1 + 3u;
    TF_R(17) TF_R(29) TF_R(16) TF_R(24)
    x0 += ks1; x1 += ks2 + 4u;
    TF_R(13) TF_R(15) TF_R(26) TF_R(6)
    x0 += ks2; x1 += ks0 + 5u;
#undef TF_R
    o0 = x0; o1 = x1;
}

// ---------------- bucket-sorted structure over 4096 random keys ------------
// Top-12-bit counting (avg 1 elem/bucket). hist = u32[4096]. Within bucket
// b, stable order == ascending (low20(key) << 12 | idx) as u32 (idx unique,
// < 4096) -> exact JAX stable-sort tie-break.
// Leaves: hist[b] = inclusive end of run b; pack32[start..end) = run b.
__device__ __forceinline__ void build4096(
    uint32_t s0, uint32_t s1,
    uint32_t* __restrict__ pack32, uint32_t* __restrict__ hist,
    int tid, int w, int lane, uint32_t* __restrict__ wsum) {

    __syncthreads();  // prior-phase readers of pack/hist are done
    ((uint4*)hist)[tid] = make_uint4(0u, 0u, 0u, 0u);
    ((uint4*)hist)[tid + 512] = make_uint4(0u, 0u, 0u, 0u);
    // key generation overlaps the zeroing stores
    uint32_t keys[8];
#pragma unroll
    for (int e = 0; e < 8; ++e) {
        uint32_t o0, o1;
        tf2x32(s0, s1, 0u, (uint32_t)(tid + e * 512), o0, o1);
        keys[e] = o0 ^ o1;
    }
    __syncthreads();

    // histogram; atomic return value = intra-bucket arrival order
    uint32_t ord[8];
#pragma unroll
    for (int e = 0; e < 8; ++e)
        ord[e] = atomicAdd(&hist[keys[e] >> 20], 1u);
    __syncthreads();

    // prefix sum -> INCLUSIVE ends, in place (thread owns bins 8t..8t+7)
    uint4 va = ((const uint4*)hist)[tid * 2];
    uint4 vb = ((const uint4*)hist)[tid * 2 + 1];
    uint32_t ssum = va.x + va.y + va.z + va.w + vb.x + vb.y + vb.z + vb.w;
    uint32_t sc = ssum;
#pragma unroll
    for (int off = 1; off < 64; off <<= 1) {
        uint32_t t = __shfl_up(sc, off);
        if (lane >= off) sc += t;
    }
    if (lane == 63) wsum[w] = sc;
    __syncthreads();
    uint32_t ex = sc - ssum;
    for (int ww = 0; ww < w; ++ww) ex += wsum[ww];
    uint32_t p1 = ex + va.x, p2 = p1 + va.y, p3 = p2 + va.z, p4 = p3 + va.w;
    uint32_t p5 = p4 + vb.x, p6 = p5 + vb.y, p7 = p6 + vb.z, p8 = p7 + vb.w;
    ((uint4*)hist)[tid * 2] = make_uint4(p1, p2, p3, p4);
    ((uint4*)hist)[tid * 2 + 1] = make_uint4(p5, p6, p7, p8);
    __syncthreads();

    // scatter (plain write; position = bucket start + arrival order)
#pragma unroll
    for (int e = 0; e < 8; ++e) {
        uint32_t bkt = keys[e] >> 20;
        uint32_t start = bkt ? hist[bkt - 1] : 0u;
        pack32[start + ord[e]] =
            ((keys[e] & 0xFFFFFu) << 12) | (uint32_t)(tid + e * 512);
    }
}

// select: element index at sorted position s. Binary search inclusive ends
// (hist[4095] == 4096 > s always), then k-th smallest of the run.
__device__ __forceinline__ uint32_t select4096(
    const uint32_t* __restrict__ hist, const uint32_t* __restrict__ pack32,
    uint32_t s) {
    uint32_t lo = 0, hi = 4095;
#pragma unroll
    for (int it = 0; it < 12; ++it) {
        uint32_t mid = (lo + hi) >> 1;
        if (hist[mid] > s) hi = mid; else lo = mid + 1;
    }
    uint32_t b = lo;  // == hi: bucket containing position s
    uint32_t start = b ? hist[b - 1] : 0u;
    uint32_t L = hist[b] - start;
    uint32_t c = pack32[start];
    if (L > 1) {
        uint32_t k = s - start;
        for (uint32_t cand = 0; cand < L; ++cand) {
            uint32_t cc = pack32[start + cand];
            uint32_t cnt = 0;
            for (uint32_t o = 0; o < L; ++o)
                cnt += (pack32[start + o] < cc) ? 1u : 0u;
            if (cnt == k) { c = cc; break; }
        }
    }
    return c & 0xFFFu;
}

// ---------------- Fused kernel: sample-select | LDS-free dct ---------------
// grid 4608 = 512 groups x 9. rem<8 -> sample gb = grp*8+rem (4096 WGs);
// rem==8 -> dct chunk = grp (512 WGs x 512 threads = one thread per 8x8
// block). dct path: no LDS, no barriers; 8x8 DCT in FOUR row-pair passes
// (acc[2][8] = 16 regs, peak live ~40 -- fits the 64-VGPR cap, no spills;
// Y re-read per pass, input is L3-resident).
__global__ __launch_bounds__(512, 8) void fused_kernel(
    const float* __restrict__ x, float* __restrict__ out,
    uint32_t* __restrict__ ws) {
    __shared__ __align__(16) uint8_t smem[33280];  // sample path only
    __shared__ uint32_t wsum[8];

    const int tid = threadIdx.x;
    const int grp = (int)blockIdx.x / 9;
    const int rem = (int)blockIdx.x % 9;

    if (rem == 8) {
        // =================== dct path (no LDS, no barriers) ===============
        int g = grp * 512 + tid;            // one thread per 8x8 block
        int b = g >> 12;
        int rr = g & 4095;
        int ai = rr >> 6, bi = rr & 63;
        int row0 = ai * 8, col0 = bi * 8;
        size_t ib = (size_t)b * 3 * IMG_ELEMS;
        size_t ob = (size_t)b * IMG_ELEMS;

#pragma unroll 1
        for (int p = 0; p < 4; ++p) {
            float acc[2][8];  // rows 2p, 2p+1 of Q*Y
#pragma unroll
            for (int j = 0; j < 8; ++j) { acc[0][j] = 0.0f; acc[1][j] = 0.0f; }

#pragma unroll 1
            for (int k = 0; k < 8; ++k) {
                size_t off = ib + (size_t)(row0 + k) * HW + col0;
                float y[8];
                {
                    float4 r0 = *(const float4*)(x + off);
                    float4 g0 = *(const float4*)(x + off + IMG_ELEMS);
                    float4 b0 = *(const float4*)(x + off + 2 * IMG_ELEMS);
                    y[0] = (0.299f * (r0.x * 255.0f) + 0.587f * (g0.x * 255.0f) +
                            0.114f * (b0.x * 255.0f)) / 255.0f;
                    y[1] = (0.299f * (r0.y * 255.0f) + 0.587f * (g0.y * 255.0f) +
                            0.114f * (b0.y * 255.0f)) / 255.0f;
                    y[2] = (0.299f * (r0.z * 255.0f) + 0.587f * (g0.z * 255.0f) +
                            0.114f * (b0.z * 255.0f)) / 255.0f;
                    y[3] = (0.299f * (r0.w * 255.0f) + 0.587f * (g0.w * 255.0f) +
                            0.114f * (b0.w * 255.0f)) / 255.0f;
                }
                {
                    float4 r1 = *(const float4*)(x + off + 4);
                    float4 g1 = *(const float4*)(x + off + IMG_ELEMS + 4);
                    float4 b1 = *(const float4*)(x + off + 2 * IMG_ELEMS + 4);
                    y[4] = (0.299f * (r1.x * 255.0f) + 0.587f * (g1.x * 255.0f) +
                            0.114f * (b1.x * 255.0f)) / 255.0f;
                    y[5] = (0.299f * (r1.y * 255.0f) + 0.587f * (g1.y * 255.0f) +
                            0.114f * (b1.y * 255.0f)) / 255.0f;
                    y[6] = (0.299f * (r1.z * 255.0f) + 0.587f * (g1.z * 255.0f) +
                            0.114f * (b1.z * 255.0f)) / 255.0f;
                    y[7] = (0.299f * (r1.w * 255.0f) + 0.587f * (g1.w * 255.0f) +
                            0.114f * (b1.w * 255.0f)) / 255.0f;
                }
                float q0 = Qc[p * 2][k], q1 = Qc[p * 2 + 1][k];
#pragma unroll
                for (int j = 0; j < 8; ++j) {
                    acc[0][j] += q0 * y[j];
                    acc[1][j] += q1 * y[j];
                }
            }

#pragma unroll
            for (int i2 = 0; i2 < 2; ++i2) {
                float d[8];
#pragma unroll
                for (int j = 0; j < 8; ++j) {
                    float s = 0.0f;
#pragma unroll
                    for (int k = 0; k < 8; ++k) s += acc[i2][k] * Qc[j][k];
                    d[j] = s;
                }
                float4* o = (float4*)(out + ob +
                                      (size_t)(row0 + p * 2 + i2) * HW + col0);
                o[0] = make_float4(d[0], d[1], d[2], d[3]);
                o[1] = make_float4(d[4], d[5], d[6], d[7]);
            }
        }
    } else {
        // =================== sample-select path ===========================
        uint32_t* pack32 = (uint32_t*)smem;                    // 16 KB
        uint32_t* hist = (uint32_t*)(smem + 16384);            // 16 KB
        uint16_t* jsel = (uint16_t*)(smem + 32768);            // 512 B

        const int w = tid >> 6;
        const int lane = tid & 63;
        const int gb = grp * 8 + rem;  // b*64 + c

        uint32_t k0, k1, n0, n1, sA0, sA1, sB0, sB1;
        tf2x32(0u, 0u, 0u, (uint32_t)gb, k0, k1);
        tf2x32(k0, k1, 0u, 0u, n0, n1);     // key after round 0
        tf2x32(k0, k1, 0u, 1u, sA0, sA1);   // round-0 subkey
        tf2x32(n0, n1, 0u, 1u, sB0, sB1);   // round-1 subkey

        // round 1: j_s = element at sorted position s (s < 250)
        build4096(sB0, sB1, pack32, hist, tid, w, lane, wsum);
        __syncthreads();
        if (tid < NSAMPLE)
            jsel[tid] = (uint16_t)select4096(hist, pack32, (uint32_t)tid);
        // build4096's leading __syncthreads orders select reads before zeroing

        // round 0: i = element at sorted position j_s; emit img offset
        build4096(sA0, sA1, pack32, hist, tid, w, lane, wsum);
        __syncthreads();

        int b = gb >> 6, c = gb & 63;
        int z = ZIGZAG[c];
        int i0z = z >> 3, j0z = z & 7;
        if (tid < NSAMPLE) {
            uint32_t i = select4096(hist, pack32, (uint32_t)jsel[tid]);
            int ai = (int)i >> 6, bi = (int)i & 63;
            ws[(size_t)gb * 256 + tid] =
                (uint32_t)((size_t)b * IMG_ELEMS +
                           (size_t)(ai * 8 + i0z) * HW + (bi * 8 + j0z));
        }
    }
}

// ---------------- gather: out2[gb,s] = img[ws[gb,s]] -----------------------
__global__ __launch_bounds__(256) void gather_kernel(
    const float* __restrict__ img, const uint32_t* __restrict__ ws,
    float* __restrict__ out2) {
    const int gb = blockIdx.x;
    const int s = threadIdx.x;
    if (s < NSAMPLE)
        out2[(size_t)gb * NSAMPLE + s] = img[ws[(size_t)gb * 256 + s]];
}

extern "C" void kernel_launch(void* const* d_in, const int* in_sizes, int n_in,
                              void* d_out, int out_size, void* d_ws, size_t ws_size,
                              hipStream_t stream) {
    const float* x = (const float*)d_in[0];
    float* out = (float*)d_out;
    uint32_t* ws = (uint32_t*)d_ws;
    fused_kernel<<<512 * 9, 512, 0, stream>>>(x, out, ws);
    gather_kernel<<<BATCH * 64, 256, 0, stream>>>(
        out, ws, out + (size_t)BATCH * IMG_ELEMS);
}

// Round 8
// 359.699 us; speedup vs baseline: 1.1437x; 1.1437x over previous
//
#include <hip/hip_runtime.h>
#include <hip/hip_bf16.h>
#include <cstdint>

// ---------------------------------------------------------------------------
// Sampled DCT2: (1) luminance + per-8x8-block 2D DCT -> [64,1,512,512]
//               (2) exact JAX threefry permutation sampling -> [64,64,250]
//
// R12: HOMOGENEOUS phase fusion. R5/R6 fused heterogeneous WGs (dct-only vs
// sample-only) and lost to slot-packing asymmetry (214/184 vs serial ~192).
// R7 lost to L3 fall-off (4x input re-read: FETCH 192->348 MB). This round:
// every WG is identical -- phase 1 = strip dct for ONE (batch, block-row)
// (8x512 px, 16 KB LDS, 1 barrier; input read exactly once), phase 2 =
// sample-select for the same gb (verified inverse-select, u32 hist).
// WG retirement staggers the phases: fresh WGs run memory-bound dct while
// co-resident WGs run VALU-bound sample -> pipes mix by construction.
// No dct->sample dependency inside the kernel (sample only writes ws);
// the trailing gather resolves ws against the completed img.
//
// Sample algorithm (verified bit-exact): two counting builds; select(s) =
// binary search of inclusive ends + k-th smallest of the (avg len 1)
// bucket run; final[s] = select0(select1(s)).
// R3 lesson: generic rotl -> compiler picks v_alignbit / SALU; don't force.
// R7 lesson: input re-reads beyond 2x fall off L3; read input ONCE.
// ---------------------------------------------------------------------------

#define BATCH 64
#define HW 512
#define NBLK 4096
#define NSAMPLE 250
#define IMG_ELEMS (HW * HW)

#define A0 0.35355339059327373f
#define A1 0.49039264020161522f
#define A2 0.46193976625564337f
#define A3 0.41573480615127262f
#define A4 0.35355339059327379f
#define A5 0.27778511650980111f
#define A6 0.19134171618254492f
#define A7 0.09754516100806412f

__constant__ float Qc[8][8] = {
    { A0,  A0,  A0,  A0,  A0,  A0,  A0,  A0},
    { A1,  A3,  A5,  A7, -A7, -A5, -A3, -A1},
    { A2,  A6, -A6, -A2, -A2, -A6,  A6,  A2},
    { A3, -A7, -A1, -A5,  A5,  A1,  A7, -A3},
    { A4, -A4, -A4,  A4,  A4, -A4, -A4,  A4},
    { A5, -A1,  A7,  A3, -A3, -A7,  A1, -A5},
    { A6, -A2,  A2, -A6, -A6,  A2, -A2,  A6},
    { A7, -A5,  A3, -A1,  A1, -A3,  A5, -A7},
};

__constant__ int ZIGZAG[64] = {
    0, 1, 8, 16, 9, 2, 3, 10, 17, 24, 32, 25, 18, 11, 4, 5,
    12, 19, 26, 33, 40, 48, 41, 34, 27, 20, 13, 6, 7, 14, 21, 28,
    35, 42, 49, 56, 57, 50, 43, 36, 29, 22, 15, 23, 30, 37, 44, 51,
    58, 59, 52, 45, 38, 31, 39, 46, 53, 60, 61, 54, 47, 55, 62, 63
};

// ---------------- Threefry-2x32 (exact JAX rounds) -------------------------
__device__ __forceinline__ uint32_t rotl32(uint32_t v, int d) {
    return (v << d) | (v >> (32 - d));
}

__device__ __forceinline__ void tf2x32(uint32_t k0, uint32_t k1,
                                       uint32_t x0, uint32_t x1,
                                       uint32_t& o0, uint32_t& o1) {
    uint32_t ks0 = k0, ks1 = k1, ks2 = k0 ^ k1 ^ 0x1BD11BDAu;
    x0 += ks0; x1 += ks1;
#define TF_R(r) { x0 += x1; x1 = rotl32(x1, r); x1 ^= x0; }
    TF_R(13) TF_R(15) TF_R(26) TF_R(6)
    x0 += ks1; x1 += ks2 + 1u;
    TF_R(17) TF_R(29) TF_R(16) TF_R(24)
    x0 += ks2; x1 += ks0 + 2u;
    TF_R(13) TF_R(15) TF_R(26) TF_R(6)
    x0 += ks0; x1 += ks1 + 3u;
    TF_R(17) TF_R(29) TF_R(16) TF_R(24)
    x0 += ks1; x1 += ks2 + 4u;
    TF_R(13) TF_R(15) TF_R(26) TF_R(6)
    x0 += ks2; x1 += ks0 + 5u;
#undef TF_R
    o0 = x0; o1 = x1;
}

// ---------------- bucket-sorted structure over 4096 random keys ------------
// Top-12-bit counting (avg 1 elem/bucket). hist = u32[4096]. Within bucket
// b, stable order == ascending (low20(key) << 12 | idx) as u32 (idx unique,
// < 4096) -> exact JAX stable-sort tie-break.
// Leaves: hist[b] = inclusive end of run b; pack32[start..end) = run b.
__device__ __forceinline__ void build4096(
    uint32_t s0, uint32_t s1,
    uint32_t* __restrict__ pack32, uint32_t* __restrict__ hist,
    int tid, int w, int lane, uint32_t* __restrict__ wsum) {

    __syncthreads();  // prior-phase readers of pack/hist are done
    ((uint4*)hist)[tid] = make_uint4(0u, 0u, 0u, 0u);
    ((uint4*)hist)[tid + 512] = make_uint4(0u, 0u, 0u, 0u);
    // key generation overlaps the zeroing stores
    uint32_t keys[8];
#pragma unroll
    for (int e = 0; e < 8; ++e) {
        uint32_t o0, o1;
        tf2x32(s0, s1, 0u, (uint32_t)(tid + e * 512), o0, o1);
        keys[e] = o0 ^ o1;
    }
    __syncthreads();

    // histogram; atomic return value = intra-bucket arrival order
    uint32_t ord[8];
#pragma unroll
    for (int e = 0; e < 8; ++e)
        ord[e] = atomicAdd(&hist[keys[e] >> 20], 1u);
    __syncthreads();

    // prefix sum -> INCLUSIVE ends, in place (thread owns bins 8t..8t+7)
    uint4 va = ((const uint4*)hist)[tid * 2];
    uint4 vb = ((const uint4*)hist)[tid * 2 + 1];
    uint32_t ssum = va.x + va.y + va.z + va.w + vb.x + vb.y + vb.z + vb.w;
    uint32_t sc = ssum;
#pragma unroll
    for (int off = 1; off < 64; off <<= 1) {
        uint32_t t = __shfl_up(sc, off);
        if (lane >= off) sc += t;
    }
    if (lane == 63) wsum[w] = sc;
    __syncthreads();
    uint32_t ex = sc - ssum;
    for (int ww = 0; ww < w; ++ww) ex += wsum[ww];
    uint32_t p1 = ex + va.x, p2 = p1 + va.y, p3 = p2 + va.z, p4 = p3 + va.w;
    uint32_t p5 = p4 + vb.x, p6 = p5 + vb.y, p7 = p6 + vb.z, p8 = p7 + vb.w;
    ((uint4*)hist)[tid * 2] = make_uint4(p1, p2, p3, p4);
    ((uint4*)hist)[tid * 2 + 1] = make_uint4(p5, p6, p7, p8);
    __syncthreads();

    // scatter (plain write; position = bucket start + arrival order)
#pragma unroll
    for (int e = 0; e < 8; ++e) {
        uint32_t bkt = keys[e] >> 20;
        uint32_t start = bkt ? hist[bkt - 1] : 0u;
        pack32[start + ord[e]] =
            ((keys[e] & 0xFFFFFu) << 12) | (uint32_t)(tid + e * 512);
    }
}

// select: element index at sorted position s. Binary search inclusive ends
// (hist[4095] == 4096 > s always), then k-th smallest of the run.
__device__ __forceinline__ uint32_t select4096(
    const uint32_t* __restrict__ hist, const uint32_t* __restrict__ pack32,
    uint32_t s) {
    uint32_t lo = 0, hi = 4095;
#pragma unroll
    for (int it = 0; it < 12; ++it) {
        uint32_t mid = (lo + hi) >> 1;
        if (hist[mid] > s) hi = mid; else lo = mid + 1;
    }
    uint32_t b = lo;  // == hi: bucket containing position s
    uint32_t start = b ? hist[b - 1] : 0u;
    uint32_t L = hist[b] - start;
    uint32_t c = pack32[start];
    if (L > 1) {
        uint32_t k = s - start;
        for (uint32_t cand = 0; cand < L; ++cand) {
            uint32_t cc = pack32[start + cand];
            uint32_t cnt = 0;
            for (uint32_t o = 0; o < L; ++o)
                cnt += (pack32[start + o] < cc) ? 1u : 0u;
            if (cnt == k) { c = cc; break; }
        }
    }
    return c & 0xFFFu;
}

// ---------------- Fused kernel: per-WG {strip dct; sample-select} ----------
// 4096 identical WGs of 512 threads. WG gb:
//   phase 1: dct of block-row (b = gb>>6, ai = gb&63): 8 rows x 512 cols,
//            both 256-col halves at once (h = tid>>8). 16 KB LDS, 1 barrier.
//   phase 2: sample-select for gb (writes 250 img offsets to ws).
// Phases are independent (sample never reads img); gather joins them.
__global__ __launch_bounds__(512, 8) void fused_kernel(
    const float* __restrict__ x, float* __restrict__ out,
    uint32_t* __restrict__ ws) {
    __shared__ __align__(16) uint8_t smem[33280];
    __shared__ uint32_t wsum[8];

    const int tid = threadIdx.x;
    const int gb = blockIdx.x;          // b*64 + (ai | c)

    // =================== phase 1: strip dct ===================
    {
        float* ylds = (float*)smem;     // [2][8][8][32] = 16 KB
        const int b = gb >> 6;
        const int ai = gb & 63;
        const int row0 = ai * 8;
        const int h = tid >> 8;
        const int t2 = tid & 255;
        const int colbase = h * 256;

        {   // stage: thread loads 8 px x 3 ch of row k, col-group cg
            const int k = t2 >> 5;
            const int cg = t2 & 31;
            size_t off = (size_t)b * 3 * IMG_ELEMS + (size_t)(row0 + k) * HW +
                         colbase + cg * 8;
            float4 r0 = *(const float4*)(x + off);
            float4 r1 = *(const float4*)(x + off + 4);
            float4 g0 = *(const float4*)(x + off + IMG_ELEMS);
            float4 g1 = *(const float4*)(x + off + IMG_ELEMS + 4);
            float4 b0 = *(const float4*)(x + off + 2 * IMG_ELEMS);
            float4 b1 = *(const float4*)(x + off + 2 * IMG_ELEMS + 4);
            float R[8] = {r0.x, r0.y, r0.z, r0.w, r1.x, r1.y, r1.z, r1.w};
            float G[8] = {g0.x, g0.y, g0.z, g0.w, g1.x, g1.y, g1.z, g1.w};
            float B[8] = {b0.x, b0.y, b0.z, b0.w, b1.x, b1.y, b1.z, b1.w};
            float* yh = ylds + h * 2048 + k * 256;
#pragma unroll
            for (int jj = 0; jj < 8; ++jj) {
                float y = (0.299f * (R[jj] * 255.0f) + 0.587f * (G[jj] * 255.0f) +
                           0.114f * (B[jj] * 255.0f)) / 255.0f;
                yh[jj * 32 + cg] = y;   // bank = cg: 2-way (free)
            }
        }
        __syncthreads();

        {   // compute: thread emits one output row of one 8x8 block
            const int i = t2 >> 5;
            const int bi = t2 & 31;
            const float* yh = ylds + h * 2048;
            float qrow[8];
#pragma unroll
            for (int k = 0; k < 8; ++k) qrow[k] = Qc[i][k];

            float acc[8];
#pragma unroll
            for (int j = 0; j < 8; ++j) acc[j] = 0.0f;
#pragma unroll
            for (int k = 0; k < 8; ++k) {
#pragma unroll
                for (int j = 0; j < 8; ++j)
                    acc[j] += qrow[k] * yh[k * 256 + j * 32 + bi];  // c-free
            }

            float d[8];
#pragma unroll
            for (int j = 0; j < 8; ++j) {
                float s = 0.0f;
#pragma unroll
                for (int k = 0; k < 8; ++k) s += acc[k] * Qc[j][k];
                d[j] = s;
            }
            float4* o = (float4*)(out + (size_t)b * IMG_ELEMS +
                                  (size_t)(row0 + i) * HW + colbase + bi * 8);
            o[0] = make_float4(d[0], d[1], d[2], d[3]);
            o[1] = make_float4(d[4], d[5], d[6], d[7]);
        }
    }
    // build4096's leading __syncthreads orders phase-1 LDS reads before
    // any phase-2 overwrite (pack32 aliases ylds; first write is post-bar).

    // =================== phase 2: sample-select ===================
    {
        uint32_t* pack32 = (uint32_t*)smem;                    // 16 KB
        uint32_t* hist = (uint32_t*)(smem + 16384);            // 16 KB
        uint16_t* jsel = (uint16_t*)(smem + 32768);            // 512 B

        const int w = tid >> 6;
        const int lane = tid & 63;

        uint32_t k0, k1, n0, n1, sA0, sA1, sB0, sB1;
        tf2x32(0u, 0u, 0u, (uint32_t)gb, k0, k1);
        tf2x32(k0, k1, 0u, 0u, n0, n1);     // key after round 0
        tf2x32(k0, k1, 0u, 1u, sA0, sA1);   // round-0 subkey
        tf2x32(n0, n1, 0u, 1u, sB0, sB1);   // round-1 subkey

        // round 1: j_s = element at sorted position s (s < 250)
        build4096(sB0, sB1, pack32, hist, tid, w, lane, wsum);
        __syncthreads();
        if (tid < NSAMPLE)
            jsel[tid] = (uint16_t)select4096(hist, pack32, (uint32_t)tid);
        // build4096's leading __syncthreads orders select reads before zeroing

        // round 0: i = element at sorted position j_s; emit img offset
        build4096(sA0, sA1, pack32, hist, tid, w, lane, wsum);
        __syncthreads();

        int b = gb >> 6, c = gb & 63;
        int z = ZIGZAG[c];
        int i0z = z >> 3, j0z = z & 7;
        if (tid < NSAMPLE) {
            uint32_t i = select4096(hist, pack32, (uint32_t)jsel[tid]);
            int ai = (int)i >> 6, bi = (int)i & 63;
            ws[(size_t)gb * 256 + tid] =
                (uint32_t)((size_t)b * IMG_ELEMS +
                           (size_t)(ai * 8 + i0z) * HW + (bi * 8 + j0z));
        }
    }
}

// ---------------- gather: out2[gb,s] = img[ws[gb,s]] -----------------------
__global__ __launch_bounds__(256) void gather_kernel(
    const float* __restrict__ img, const uint32_t* __restrict__ ws,
    float* __restrict__ out2) {
    const int gb = blockIdx.x;
    const int s = threadIdx.x;
    if (s < NSAMPLE)
        out2[(size_t)gb * NSAMPLE + s] = img[ws[(size_t)gb * 256 + s]];
}

extern "C" void kernel_launch(void* const* d_in, const int* in_sizes, int n_in,
                              void* d_out, int out_size, void* d_ws, size_t ws_size,
                              hipStream_t stream) {
    const float* x = (const float*)d_in[0];
    float* out = (float*)d_out;
    uint32_t* ws = (uint32_t*)d_ws;
    fused_kernel<<<NBLK, 512, 0, stream>>>(x, out, ws);
    gather_kernel<<<BATCH * 64, 256, 0, stream>>>(
        out, ws, out + (size_t)BATCH * IMG_ELEMS);
}

// Round 9
// 359.080 us; speedup vs baseline: 1.1456x; 1.0017x over previous
//
#include <hip/hip_runtime.h>
#include <hip/hip_bf16.h>
#include <cstdint>

// ---------------------------------------------------------------------------
// Sampled DCT2: (1) luminance + per-8x8-block 2D DCT -> [64,1,512,512]
//               (2) exact JAX threefry permutation sampling -> [64,64,250]
//
// R13: homogeneous phase fusion retained (R8: 149us fused, occ 77%).
// DS-pipe pressure cuts (VALUBusy 81% -> target ~90%):
//  * dct two-stage: stage A computes a column of Q*Y (8 ds_reads + 64 FMA),
//    stores to a 2nd LDS region; stage B reads 8, 64 FMA, writes out.
//    Same FLOPs, bit-identical summation order; DS ops 72 -> 32 per thread.
//  * round-1 candidate-only: only elements with bucket-start < 250 can have
//    rank < 250. Scatter just those (~255 of 4096; ~0.5 writes/thread) and
//    have them write jsel[rank] = idx directly from a run scan. Deletes the
//    full round-1 scatter AND the 250 x 12-probe binary searches. Bit-exact.
//  Round 0 unchanged: full scatter + select (arbitrary query positions).
//
// Lessons ledger: R3 generic rotl (compiler picks alignbit/SALU); R5 no
// heterogeneous WG split; R7 input re-reads beyond 2x fall off L3 (read
// once); R8 homogeneous phase fusion works (pipes mix by construction).
// ---------------------------------------------------------------------------

#define BATCH 64
#define HW 512
#define NBLK 4096
#define NSAMPLE 250
#define IMG_ELEMS (HW * HW)

#define A0 0.35355339059327373f
#define A1 0.49039264020161522f
#define A2 0.46193976625564337f
#define A3 0.41573480615127262f
#define A4 0.35355339059327379f
#define A5 0.27778511650980111f
#define A6 0.19134171618254492f
#define A7 0.09754516100806412f

__constant__ float Qc[8][8] = {
    { A0,  A0,  A0,  A0,  A0,  A0,  A0,  A0},
    { A1,  A3,  A5,  A7, -A7, -A5, -A3, -A1},
    { A2,  A6, -A6, -A2, -A2, -A6,  A6,  A2},
    { A3, -A7, -A1, -A5,  A5,  A1,  A7, -A3},
    { A4, -A4, -A4,  A4,  A4, -A4, -A4,  A4},
    { A5, -A1,  A7,  A3, -A3, -A7,  A1, -A5},
    { A6, -A2,  A2, -A6, -A6,  A2, -A2,  A6},
    { A7, -A5,  A3, -A1,  A1, -A3,  A5, -A7},
};

__constant__ int ZIGZAG[64] = {
    0, 1, 8, 16, 9, 2, 3, 10, 17, 24, 32, 25, 18, 11, 4, 5,
    12, 19, 26, 33, 40, 48, 41, 34, 27, 20, 13, 6, 7, 14, 21, 28,
    35, 42, 49, 56, 57, 50, 43, 36, 29, 22, 15, 23, 30, 37, 44, 51,
    58, 59, 52, 45, 38, 31, 39, 46, 53, 60, 61, 54, 47, 55, 62, 63
};

// ---------------- Threefry-2x32 (exact JAX rounds) -------------------------
__device__ __forceinline__ uint32_t rotl32(uint32_t v, int d) {
    return (v << d) | (v >> (32 - d));
}

__device__ __forceinline__ void tf2x32(uint32_t k0, uint32_t k1,
                                       uint32_t x0, uint32_t x1,
                                       uint32_t& o0, uint32_t& o1) {
    uint32_t ks0 = k0, ks1 = k1, ks2 = k0 ^ k1 ^ 0x1BD11BDAu;
    x0 += ks0; x1 += ks1;
#define TF_R(r) { x0 += x1; x1 = rotl32(x1, r); x1 ^= x0; }
    TF_R(13) TF_R(15) TF_R(26) TF_R(6)
    x0 += ks1; x1 += ks2 + 1u;
    TF_R(17) TF_R(29) TF_R(16) TF_R(24)
    x0 += ks2; x1 += ks0 + 2u;
    TF_R(13) TF_R(15) TF_R(26) TF_R(6)
    x0 += ks0; x1 += ks1 + 3u;
    TF_R(17) TF_R(29) TF_R(16) TF_R(24)
    x0 += ks1; x1 += ks2 + 4u;
    TF_R(13) TF_R(15) TF_R(26) TF_R(6)
    x0 += ks2; x1 += ks0 + 5u;
#undef TF_R
    o0 = x0; o1 = x1;
}

// ---------------- common build: hist (inclusive ends) + arrival order ------
// Top-12-bit counting (avg 1 elem/bucket). hist = u32[4096]. Within bucket
// b, stable order == ascending (low20(key) << 12 | idx) as u32 (idx unique,
// < 4096) -> exact JAX stable-sort tie-break.
__device__ __forceinline__ void build_common(
    uint32_t s0, uint32_t s1, uint32_t* __restrict__ hist,
    int tid, int w, int lane, uint32_t* __restrict__ wsum,
    uint32_t keys[8], uint32_t ord[8]) {

    __syncthreads();  // prior-phase readers of pack/hist are done
    ((uint4*)hist)[tid] = make_uint4(0u, 0u, 0u, 0u);
    ((uint4*)hist)[tid + 512] = make_uint4(0u, 0u, 0u, 0u);
    // key generation overlaps the zeroing stores
#pragma unroll
    for (int e = 0; e < 8; ++e) {
        uint32_t o0, o1;
        tf2x32(s0, s1, 0u, (uint32_t)(tid + e * 512), o0, o1);
        keys[e] = o0 ^ o1;
    }
    __syncthreads();

    // histogram; atomic return value = intra-bucket arrival order
#pragma unroll
    for (int e = 0; e < 8; ++e)
        ord[e] = atomicAdd(&hist[keys[e] >> 20], 1u);
    __syncthreads();

    // prefix sum -> INCLUSIVE ends, in place (thread owns bins 8t..8t+7)
    uint4 va = ((const uint4*)hist)[tid * 2];
    uint4 vb = ((const uint4*)hist)[tid * 2 + 1];
    uint32_t ssum = va.x + va.y + va.z + va.w + vb.x + vb.y + vb.z + vb.w;
    uint32_t sc = ssum;
#pragma unroll
    for (int off = 1; off < 64; off <<= 1) {
        uint32_t t = __shfl_up(sc, off);
        if (lane >= off) sc += t;
    }
    if (lane == 63) wsum[w] = sc;
    __syncthreads();
    uint32_t ex = sc - ssum;
    for (int ww = 0; ww < w; ++ww) ex += wsum[ww];
    uint32_t p1 = ex + va.x, p2 = p1 + va.y, p3 = p2 + va.z, p4 = p3 + va.w;
    uint32_t p5 = p4 + vb.x, p6 = p5 + vb.y, p7 = p6 + vb.z, p8 = p7 + vb.w;
    ((uint4*)hist)[tid * 2] = make_uint4(p1, p2, p3, p4);
    ((uint4*)hist)[tid * 2 + 1] = make_uint4(p5, p6, p7, p8);
    __syncthreads();
}

// select: element index at sorted position s. Binary search inclusive ends
// (hist[4095] == 4096 > s always), then k-th smallest of the run.
__device__ __forceinline__ uint32_t select4096(
    const uint32_t* __restrict__ hist, const uint32_t* __restrict__ pack32,
    uint32_t s) {
    uint32_t lo = 0, hi = 4095;
#pragma unroll
    for (int it = 0; it < 12; ++it) {
        uint32_t mid = (lo + hi) >> 1;
        if (hist[mid] > s) hi = mid; else lo = mid + 1;
    }
    uint32_t b = lo;  // == hi: bucket containing position s
    uint32_t start = b ? hist[b - 1] : 0u;
    uint32_t L = hist[b] - start;
    uint32_t c = pack32[start];
    if (L > 1) {
        uint32_t k = s - start;
        for (uint32_t cand = 0; cand < L; ++cand) {
            uint32_t cc = pack32[start + cand];
            uint32_t cnt = 0;
            for (uint32_t o = 0; o < L; ++o)
                cnt += (pack32[start + o] < cc) ? 1u : 0u;
            if (cnt == k) { c = cc; break; }
        }
    }
    return c & 0xFFFu;
}

// ---------------- Fused kernel: per-WG {strip dct; sample-select} ----------
// 4096 identical WGs of 512 threads. WG gb:
//   phase 1: dct of block-row (b = gb>>6, ai = gb&63), two-stage via LDS.
//   phase 2: sample-select for gb (writes 250 img offsets to ws).
__global__ __launch_bounds__(512, 8) void fused_kernel(
    const float* __restrict__ x, float* __restrict__ out,
    uint32_t* __restrict__ ws) {
    __shared__ __align__(16) uint8_t smem[33280];
    __shared__ uint32_t wsum[8];

    const int tid = threadIdx.x;
    const int gb = blockIdx.x;          // b*64 + (ai | c)

    // =================== phase 1: strip dct (two-stage) ===================
    {
        const int b = gb >> 6;
        const int ai = gb & 63;
        const int row0 = ai * 8;
        const int h = tid >> 8;         // column half (0/1)
        const int t2 = tid & 255;
        const int colbase = h * 256;
        float* ybase = (float*)smem + h * 2048;            // Y   [k][c'][bi]
        float* ubase = (float*)(smem + 16384) + h * 2048;  // Q*Y [i][c'][bi]

        {   // stage 0: load 8 px x 3 ch of row k, col-group cg -> luminance
            const int k = t2 >> 5;
            const int cg = t2 & 31;
            size_t off = (size_t)b * 3 * IMG_ELEMS + (size_t)(row0 + k) * HW +
                         colbase + cg * 8;
            float4 r0 = *(const float4*)(x + off);
            float4 r1 = *(const float4*)(x + off + 4);
            float4 g0 = *(const float4*)(x + off + IMG_ELEMS);
            float4 g1 = *(const float4*)(x + off + IMG_ELEMS + 4);
            float4 b0 = *(const float4*)(x + off + 2 * IMG_ELEMS);
            float4 b1 = *(const float4*)(x + off + 2 * IMG_ELEMS + 4);
            float R[8] = {r0.x, r0.y, r0.z, r0.w, r1.x, r1.y, r1.z, r1.w};
            float G[8] = {g0.x, g0.y, g0.z, g0.w, g1.x, g1.y, g1.z, g1.w};
            float B[8] = {b0.x, b0.y, b0.z, b0.w, b1.x, b1.y, b1.z, b1.w};
            float* yh = ybase + k * 256;
#pragma unroll
            for (int jj = 0; jj < 8; ++jj) {
                float y = (0.299f * (R[jj] * 255.0f) + 0.587f * (G[jj] * 255.0f) +
                           0.114f * (B[jj] * 255.0f)) / 255.0f;
                yh[jj * 32 + cg] = y;   // bank = cg: 2 lanes/bank (free)
            }
        }
        __syncthreads();

        {   // stage A: thread owns column (c' = t2>>5, bi = t2&31):
            // u[i] = sum_k Q[i][k] * Y[k][c']  (8 ds_reads, 64 FMA, 8 writes)
            const int cp = t2 >> 5;
            const int bi = t2 & 31;
            float y[8];
#pragma unroll
            for (int k = 0; k < 8; ++k)
                y[k] = ybase[k * 256 + cp * 32 + bi];
            float u[8];
#pragma unroll
            for (int i = 0; i < 8; ++i) {
                float s = 0.0f;
#pragma unroll
                for (int k = 0; k < 8; ++k) s += Qc[i][k] * y[k];
                u[i] = s;
            }
#pragma unroll
            for (int i = 0; i < 8; ++i)
                ubase[i * 256 + cp * 32 + bi] = u[i];
        }
        __syncthreads();

        {   // stage B: thread owns output row (i = t2>>5) of block bi:
            // d[j] = sum_c (QY)[i][c] * Q[j][c]  (8 ds_reads, 64 FMA)
            const int i = t2 >> 5;
            const int bi = t2 & 31;
            float qy[8];
#pragma unroll
            for (int c = 0; c < 8; ++c)
                qy[c] = ubase[i * 256 + c * 32 + bi];
            float d[8];
#pragma unroll
            for (int j = 0; j < 8; ++j) {
                float s = 0.0f;
#pragma unroll
                for (int c = 0; c < 8; ++c) s += qy[c] * Qc[j][c];
                d[j] = s;
            }
            float4* o = (float4*)(out + (size_t)b * IMG_ELEMS +
                                  (size_t)(row0 + i) * HW + colbase + bi * 8);
            o[0] = make_float4(d[0], d[1], d[2], d[3]);
            o[1] = make_float4(d[4], d[5], d[6], d[7]);
        }
    }
    // build_common's leading __syncthreads orders phase-1 LDS reads before
    // phase-2 overwrites (pack32 aliases Y region; hist aliases U region).

    // =================== phase 2: sample-select ===================
    {
        uint32_t* pack32 = (uint32_t*)smem;                    // 16 KB
        uint32_t* hist = (uint32_t*)(smem + 16384);            // 16 KB
        uint16_t* jsel = (uint16_t*)(smem + 32768);            // 512 B

        const int w = tid >> 6;
        const int lane = tid & 63;

        uint32_t k0, k1, n0, n1, sA0, sA1, sB0, sB1;
        tf2x32(0u, 0u, 0u, (uint32_t)gb, k0, k1);
        tf2x32(k0, k1, 0u, 0u, n0, n1);     // key after round 0
        tf2x32(k0, k1, 0u, 1u, sA0, sA1);   // round-0 subkey
        tf2x32(n0, n1, 0u, 1u, sB0, sB1);   // round-1 subkey

        uint32_t keys[8], ord[8];

        // ===== round 1: jsel[s] = element at sorted position s (s<250) ====
        // Candidate-only: rank < 250 implies bucket start < 250. Scatter
        // only those runs; members rank-scan their (complete) run and write
        // jsel[rank] directly. No full scatter, no binary searches.
        build_common(sB0, sB1, hist, tid, w, lane, wsum, keys, ord);
        uint32_t starts[8];
#pragma unroll
        for (int e = 0; e < 8; ++e) {
            uint32_t bkt = keys[e] >> 20;
            starts[e] = bkt ? hist[bkt - 1] : 0u;
            if (starts[e] < NSAMPLE)
                pack32[starts[e] + ord[e]] =
                    ((keys[e] & 0xFFFFFu) << 12) | (uint32_t)(tid + e * 512);
        }
        __syncthreads();
#pragma unroll
        for (int e = 0; e < 8; ++e) {
            if (starts[e] < NSAMPLE) {
                uint32_t bkt = keys[e] >> 20;
                uint32_t end = hist[bkt];
                uint32_t self =
                    ((keys[e] & 0xFFFFFu) << 12) | (uint32_t)(tid + e * 512);
                uint32_t r = starts[e];
                for (uint32_t p = starts[e]; p < end; ++p)
                    r += (pack32[p] < self) ? 1u : 0u;
                if (r < NSAMPLE) jsel[r] = (uint16_t)(tid + e * 512);
            }
        }

        // ===== round 0: i = element at sorted position j_s; emit offset ===
        build_common(sA0, sA1, hist, tid, w, lane, wsum, keys, ord);
        // full scatter (query positions are arbitrary)
#pragma unroll
        for (int e = 0; e < 8; ++e) {
            uint32_t bkt = keys[e] >> 20;
            uint32_t start = bkt ? hist[bkt - 1] : 0u;
            pack32[start + ord[e]] =
                ((keys[e] & 0xFFFFFu) << 12) | (uint32_t)(tid + e * 512);
        }
        __syncthreads();

        int b = gb >> 6, c = gb & 63;
        int z = ZIGZAG[c];
        int i0z = z >> 3, j0z = z & 7;
        if (tid < NSAMPLE) {
            uint32_t i = select4096(hist, pack32, (uint32_t)jsel[tid]);
            int ai = (int)i >> 6, bi = (int)i & 63;
            ws[(size_t)gb * 256 + tid] =
                (uint32_t)((size_t)b * IMG_ELEMS +
                           (size_t)(ai * 8 + i0z) * HW + (bi * 8 + j0z));
        }
    }
}

// ---------------- gather: out2[gb,s] = img[ws[gb,s]] -----------------------
__global__ __launch_bounds__(256) void gather_kernel(
    const float* __restrict__ img, const uint32_t* __restrict__ ws,
    float* __restrict__ out2) {
    const int gb = blockIdx.x;
    const int s = threadIdx.x;
    if (s < NSAMPLE)
        out2[(size_t)gb * NSAMPLE + s] = img[ws[(size_t)gb * 256 + s]];
}

extern "C" void kernel_launch(void* const* d_in, const int* in_sizes, int n_in,
                              void* d_out, int out_size, void* d_ws, size_t ws_size,
                              hipStream_t stream) {
    const float* x = (const float*)d_in[0];
    float* out = (float*)d_out;
    uint32_t* ws = (uint32_t*)d_ws;
    fused_kernel<<<NBLK, 512, 0, stream>>>(x, out, ws);
    gather_kernel<<<BATCH * 64, 256, 0, stream>>>(
        out, ws, out + (size_t)BATCH * IMG_ELEMS);
}